// Round 19
// baseline (457.462 us; speedup 1.0000x reference)
//
#include <hip/hip_runtime.h>

#define NN 100000
#define NE 1600000
#define SF 16
#define DF 32
#define EFT 8
#define HF 64

typedef __attribute__((ext_vector_type(8))) _Float16 half8;
typedef __attribute__((ext_vector_type(4))) _Float16 half4v;
typedef __attribute__((ext_vector_type(8))) short short8;
typedef __attribute__((ext_vector_type(4))) float floatx4;

// swizzled half-index into the [256][64] h tile (128B rows, 16B-granule XOR)
__device__ inline int hswz(int row, int halfoff) {
  int gran = halfoff >> 3, sub = halfoff & 7;
  return row * 64 + ((gran ^ (row & 7)) << 3) + sub;
}

// ---------------- CSR scan ----------------
__global__ __launch_bounds__(256) void scan1_kernel(const int* __restrict__ deg,
                                                    int* __restrict__ cur,
                                                    int* __restrict__ bsums) {
  __shared__ int ts[256];
  int tid = threadIdx.x;
  int base = blockIdx.x * 1024 + tid * 4;
  int v[4];
#pragma unroll
  for (int q = 0; q < 4; ++q) v[q] = (base + q < NN) ? deg[base + q] : 0;
  int s = v[0] + v[1] + v[2] + v[3];
  ts[tid] = s;
  __syncthreads();
  for (int off = 1; off < 256; off <<= 1) {
    int t = (tid >= off) ? ts[tid - off] : 0;
    __syncthreads();
    ts[tid] += t;
    __syncthreads();
  }
  int excl = ts[tid] - s;
  if (tid == 255) bsums[blockIdx.x] = ts[255];
  int run = excl;
#pragma unroll
  for (int q = 0; q < 4; ++q) {
    if (base + q < NN) cur[base + q] = run;
    run += v[q];
  }
}

__global__ __launch_bounds__(256) void scan3_kernel(int* __restrict__ cur,
                                                    const int* __restrict__ bsums) {
  int i = blockIdx.x * 256 + threadIdx.x;
  int g = blockIdx.x >> 2;
  int pref = 0;
  for (int q = 0; q < g; ++q) pref += bsums[q];
  if (i < NN) cur[i] += pref;
}

// ---- setup (grid 6250): zero scattered; pack tables; hist (deg pre-zeroed) ----
__global__ __launch_bounds__(256) void setup_kernel(
    const int* __restrict__ ei,
    const float* __restrict__ W1, const float* __restrict__ W2,
    _Float16* __restrict__ WpreT, _Float16* __restrict__ w2pk,
    _Float16* __restrict__ w1epk,
    float4* __restrict__ scattered4, int* __restrict__ deg) {
  int gid = blockIdx.x * 256 + threadIdx.x;
  if (gid < 800000) {
    float4 z = {0.f, 0.f, 0.f, 0.f};
    scattered4[gid] = z;
  }
  if (gid < 128 * 64) {
    int col = gid >> 6, k = gid & 63;
    int j = col & 63;
    bool bh = col >= 64;
    float v = 0.f;
    if (k < 16) v = W1[((bh ? 16 : 0) + k) * HF + j];
    else if (k < 48) v = W1[((bh ? 64 : 32) + (k - 16)) * HF + j];
    WpreT[gid] = (_Float16)v;
  }
  if (gid < 2048) {
    // W2 B-frags: lane holds col = nt*16+lcol, k = kt*32 + kgrp*8 + q
    int lane = gid >> 5, idx = gid & 31;
    int kt = idx >> 4, nt = (idx >> 3) & 1, q = idx & 7;
    int kgrp = (lane >> 4) & 3, lcol = lane & 15;
    w2pk[gid] = (_Float16)W2[(kt * 32 + kgrp * 8 + q) * DF + nt * 16 + lcol];
  } else if (gid < 4096) {
    // W1e^T A-frags: lane<16 holds row j=lane (within jblk), k=t (k>=8 -> 0)
    int id = gid - 2048;  // lane*32 + jblk*8 + t
    int lane = id >> 5, idx = id & 31;
    int jblk = idx >> 3, t = idx & 7;
    float v = (lane < 16) ? W1[(96 + t) * HF + jblk * 16 + lane] : 0.f;
    w1epk[id] = (_Float16)v;
  }
  // hist (deg zeroed by hipMemsetAsync before this kernel)
  atomicAdd(&deg[ei[NE + gid]], 1);
}

// ---- fill: packed 32B-aligned sorted records {int r, int c, half ea[8], pad} ----
__global__ __launch_bounds__(256) void fill_kernel(
    const int* __restrict__ ei, const float* __restrict__ ea,
    int* __restrict__ cur, char* __restrict__ recs) {
  int e = blockIdx.x * 256 + threadIdx.x;
  int r = ei[e];
  int c = ei[NE + e];
  int pos = atomicAdd(&cur[c], 1);
  const float4* p = (const float4*)(ea + (size_t)e * EFT);
  float4 v0 = p[0], v1 = p[1];
  union { _Float16 h[2]; int i; } p01, p23, p45, p67;
  p01.h[0] = (_Float16)v0.x; p01.h[1] = (_Float16)v0.y;
  p23.h[0] = (_Float16)v0.z; p23.h[1] = (_Float16)v0.w;
  p45.h[0] = (_Float16)v1.x; p45.h[1] = (_Float16)v1.y;
  p67.h[0] = (_Float16)v1.z; p67.h[1] = (_Float16)v1.w;
  int4* rp = (int4*)(recs + (size_t)pos * 32);
  int4 a = {r, c, p01.i, p23.i};
  int4 b = {p45.i, p67.i, 0, 0};
  rp[0] = a;
  rp[1] = b;
}

// ---- shared pre-body: MFMA ABh for 64 nodes of this block, outb rows in obs ----
__device__ inline void pre_body(int tid, int bbase64,
                                const float* __restrict__ x_s,
                                const _Float16 (*wlds)[72],
                                const _Float16 (*obs)[32],
                                _Float16* __restrict__ ABh) {
  int lcol = tid & 15, kgrp = (tid >> 4) & 3, wid = tid >> 6;
  int nodebase = bbase64 + wid * 16;
  int nodeA = nodebase + lcol;
  int ln = wid * 16 + lcol;

  half8 a0 = {}, a1 = {};
  if (nodeA < NN) {
    if (kgrp < 2) {
      const float4* p = (const float4*)(x_s + (size_t)nodeA * SF);
      float4 v0 = p[kgrp * 2], v1 = p[kgrp * 2 + 1];
      a0[0]=(_Float16)v0.x; a0[1]=(_Float16)v0.y;
      a0[2]=(_Float16)v0.z; a0[3]=(_Float16)v0.w;
      a0[4]=(_Float16)v1.x; a0[5]=(_Float16)v1.y;
      a0[6]=(_Float16)v1.z; a0[7]=(_Float16)v1.w;
      a1 = *(const half8*)(&obs[ln][16 + kgrp * 8]);
    } else if (kgrp == 2) {
      a0 = *(const half8*)(&obs[ln][0]);
    } else {
      a0 = *(const half8*)(&obs[ln][8]);
    }
  }

  floatx4 acc[8];
#pragma unroll
  for (int nt = 0; nt < 8; ++nt) {
    half8 b0 = *(const half8*)(&wlds[nt * 16 + lcol][kgrp * 8]);
    half8 b1v = *(const half8*)(&wlds[nt * 16 + lcol][32 + kgrp * 8]);
    floatx4 c = {0.f, 0.f, 0.f, 0.f};
    c = __builtin_amdgcn_mfma_f32_16x16x32_f16(a0, b0, c, 0, 0, 0);
    c = __builtin_amdgcn_mfma_f32_16x16x32_f16(a1, b1v, c, 0, 0, 0);
    acc[nt] = c;
  }

#pragma unroll
  for (int rr = 0; rr < 4; ++rr) {
    int node = nodebase + kgrp * 4 + rr;
    if (node < NN) {
      _Float16* dst = ABh + (size_t)node * 128;
#pragma unroll
      for (int nt = 0; nt < 8; ++nt)
        dst[nt * 16 + lcol] = (_Float16)acc[nt][rr];
    }
  }
}

// ---- initpre (grid 1563): out = x_t @ F0; outb/sums; then pre MFMA ----
__global__ __launch_bounds__(256) void initpre_kernel(
    const float* __restrict__ x_t, const float* __restrict__ F0,
    const float* __restrict__ x_s, const _Float16* __restrict__ WpreT,
    float* __restrict__ out, _Float16* __restrict__ outb,
    float* __restrict__ sums, _Float16* __restrict__ ABh) {
  __shared__ _Float16 wlds[128][72];
  __shared__ _Float16 obs[64][32];
  int tid = threadIdx.x;
  for (int t = tid; t < 1024; t += 256) {
    int colr = t >> 3, kc = t & 7;
    *(half8*)(&wlds[colr][kc * 8]) = *(const half8*)(WpreT + colr * 64 + kc * 8);
  }

  int nl = tid >> 2, q = tid & 3;
  int node = blockIdx.x * 64 + nl;
  if (node < NN) {
    float o[8];
#pragma unroll
    for (int jj = 0; jj < 8; ++jj) o[jj] = 0.f;
    const float4* xt4 = (const float4*)(x_t + (size_t)node * DF);
#pragma unroll
    for (int it = 0; it < 8; ++it) {
      float4 xv = xt4[it];
#pragma unroll
      for (int k = 0; k < 4; ++k) {
        float xk = (k == 0) ? xv.x : (k == 1) ? xv.y : (k == 2) ? xv.z : xv.w;
        const float* frow = F0 + (it * 4 + k) * DF + q * 8;
        float4 f0 = *(const float4*)(frow);
        float4 f1 = *(const float4*)(frow + 4);
        o[0] = fmaf(xk, f0.x, o[0]); o[1] = fmaf(xk, f0.y, o[1]);
        o[2] = fmaf(xk, f0.z, o[2]); o[3] = fmaf(xk, f0.w, o[3]);
        o[4] = fmaf(xk, f1.x, o[4]); o[5] = fmaf(xk, f1.y, o[5]);
        o[6] = fmaf(xk, f1.z, o[6]); o[7] = fmaf(xk, f1.w, o[7]);
      }
    }
    float4* op = (float4*)(out + (size_t)node * DF + q * 8);
    float4 w0 = {o[0], o[1], o[2], o[3]};
    float4 w1 = {o[4], o[5], o[6], o[7]};
    op[0] = w0; op[1] = w1;
    half8 pk;
#pragma unroll
    for (int jj = 0; jj < 8; ++jj) pk[jj] = (_Float16)o[jj];
    *(half8*)(outb + (size_t)node * DF + q * 8) = pk;
    *(half8*)(&obs[nl][q * 8]) = pk;
    float s = o[0]+o[1]+o[2]+o[3]+o[4]+o[5]+o[6]+o[7];
    s += __shfl_xor(s, 1, 64);
    s += __shfl_xor(s, 2, 64);
    if (q == 0) sums[node] = s;
  }
  __syncthreads();
  pre_body(tid, blockIdx.x * 64, x_s, wlds, obs, ABh);
}

// ---- nodepre (grid 1563): out += scattered @ Fk; zero scattered; pre MFMA ----
__global__ __launch_bounds__(256) void nodepre_kernel(
    float* __restrict__ out, float* __restrict__ scattered,
    const float* __restrict__ Fk,
    const float* __restrict__ x_s, const _Float16* __restrict__ WpreT,
    _Float16* __restrict__ outb, float* __restrict__ sums,
    _Float16* __restrict__ ABh) {
  __shared__ _Float16 wlds[128][72];
  __shared__ _Float16 obs[64][32];
  int tid = threadIdx.x;
  for (int t = tid; t < 1024; t += 256) {
    int colr = t >> 3, kc = t & 7;
    *(half8*)(&wlds[colr][kc * 8]) = *(const half8*)(WpreT + colr * 64 + kc * 8);
  }

  int nl = tid >> 2, q = tid & 3;
  int node = blockIdx.x * 64 + nl;
  if (node < NN) {
    float o[8];
    {
      const float4* op4 = (const float4*)(out + (size_t)node * DF + q * 8);
      float4 b0 = op4[0], b1 = op4[1];
      o[0]=b0.x; o[1]=b0.y; o[2]=b0.z; o[3]=b0.w;
      o[4]=b1.x; o[5]=b1.y; o[6]=b1.z; o[7]=b1.w;
    }
    const float4* sc4 = (const float4*)(scattered + (size_t)node * DF);
#pragma unroll
    for (int it = 0; it < 8; ++it) {
      float4 sv = sc4[it];
#pragma unroll
      for (int k = 0; k < 4; ++k) {
        float sk = (k == 0) ? sv.x : (k == 1) ? sv.y : (k == 2) ? sv.z : sv.w;
        const float* frow = Fk + (it * 4 + k) * DF + q * 8;
        float4 f0 = *(const float4*)(frow);
        float4 f1 = *(const float4*)(frow + 4);
        o[0] = fmaf(sk, f0.x, o[0]); o[1] = fmaf(sk, f0.y, o[1]);
        o[2] = fmaf(sk, f0.z, o[2]); o[3] = fmaf(sk, f0.w, o[3]);
        o[4] = fmaf(sk, f1.x, o[4]); o[5] = fmaf(sk, f1.y, o[5]);
        o[6] = fmaf(sk, f1.z, o[6]); o[7] = fmaf(sk, f1.w, o[7]);
      }
    }
    float4* op = (float4*)(out + (size_t)node * DF + q * 8);
    float4 w0 = {o[0], o[1], o[2], o[3]};
    float4 w1 = {o[4], o[5], o[6], o[7]};
    op[0] = w0; op[1] = w1;
    half8 pk;
#pragma unroll
    for (int jj = 0; jj < 8; ++jj) pk[jj] = (_Float16)o[jj];
    *(half8*)(outb + (size_t)node * DF + q * 8) = pk;
    *(half8*)(&obs[nl][q * 8]) = pk;
    float s = o[0]+o[1]+o[2]+o[3]+o[4]+o[5]+o[6]+o[7];
    s += __shfl_xor(s, 1, 64);
    s += __shfl_xor(s, 2, 64);
    if (q == 0) sums[node] = s;
    // zero own quarter of scattered (loads above already consumed: the FMA
    // chain forces vmcnt wait before these stores issue)
    float4 z = {0.f, 0.f, 0.f, 0.f};
    float4* zp = (float4*)(scattered + (size_t)node * DF + q * 8);
    zp[0] = z; zp[1] = z;
  }
  __syncthreads();
  pre_body(tid, blockIdx.x * 64, x_s, wlds, obs, ABh);
}

// ---------------- edge MLP (f16 MFMA) + owner-centric epilogue ----------------
__global__ __launch_bounds__(256, 4) void edge_kernel(
    const _Float16* __restrict__ ABh, const _Float16* __restrict__ outb,
    const float* __restrict__ sums, const char* __restrict__ recs,
    const float* __restrict__ b1, const float* __restrict__ b2,
    const _Float16* __restrict__ w2pk, const _Float16* __restrict__ w1epk,
    float* __restrict__ scattered) {
  // h: [256][64] halves, 128B rows, XOR-swizzled granules (32768 B)
  // sh: [256] rows of 33 f32 (33792 B) -> union 33792 B
  __shared__ union { _Float16 h[256 * 64]; float sh[256 * 33]; } u;
  __shared__ int scol[256];
  __shared__ unsigned short l0[256], l1[256];
  __shared__ int wbase[4];
  __shared__ int cnt;

  int tid = threadIdx.x;
  int bbase = blockIdx.x * 256;
  int i = bbase + tid;  // NE % 256 == 0: always valid
  if (tid == 0) cnt = 0;
  int lcol = tid & 15, kgrp = (tid >> 4) & 3, wid = tid >> 6;
  int lane = tid & 63;

  // load packed 32B record {r, c, ea[8] f16, pad}
  const int4* rp = (const int4*)(recs + (size_t)i * 32);
  int4 ra = rp[0];
  int4 rb = rp[1];
  int r = ra.x;
  int c = ra.y;
  int4 eai = {ra.z, ra.w, rb.x, rb.y};
  scol[tid] = c;
  float s_r = sums[r], s_c = sums[c];

  // EARLY-ISSUE: stage A[r] and B[c] halves (128B each) into registers so
  // the HBM/L3 latency hides under phase-0's shuffles + MFMAs.
  half8 Ar[8], Bc[8];
  {
    const half8* arp = (const half8*)(ABh + (size_t)r * 128);
    const half8* bcp = (const half8*)(ABh + (size_t)c * 128 + 64);
#pragma unroll
    for (int q = 0; q < 8; ++q) { Ar[q] = arp[q]; Bc[q] = bcp[q]; }
  }

  float b2c0 = b2[lcol], b2c1 = b2[16 + lcol];

  // ---- phase 0: eaw^T = W1e^T @ ea via swapped MFMA -> swizzled half4 writes ----
  const _Float16* wep = w1epk + (size_t)lane * 32;
  half8 wA0 = *(const half8*)(wep);
  half8 wA1 = *(const half8*)(wep + 8);
  half8 wA2 = *(const half8*)(wep + 16);
  half8 wA3 = *(const half8*)(wep + 24);
  const float4* b1f4 = (const float4*)b1;
  float4 b1q0 = b1f4[0 + kgrp];
  float4 b1q1 = b1f4[4 + kgrp];
  float4 b1q2 = b1f4[8 + kgrp];
  float4 b1q3 = b1f4[12 + kgrp];
  bool lo16 = lane < 16;
#pragma unroll
  for (int g = 0; g < 4; ++g) {
    int src = g * 16 + lcol;
    int4 t;
    t.x = __shfl(eai.x, src, 64);
    t.y = __shfl(eai.y, src, 64);
    t.z = __shfl(eai.z, src, 64);
    t.w = __shfl(eai.w, src, 64);
    half8 zz = {};
    half8 bg = lo16 ? __builtin_bit_cast(half8, t) : zz;
    int erow = wid * 64 + g * 16 + lcol;
    __builtin_amdgcn_s_setprio(1);  // T5: favor MFMA-phase waves
    {
      floatx4 cc = {b1q0.x, b1q0.y, b1q0.z, b1q0.w};
      cc = __builtin_amdgcn_mfma_f32_16x16x32_f16(wA0, bg, cc, 0, 0, 0);
      half4v h4 = {(_Float16)cc[0], (_Float16)cc[1], (_Float16)cc[2], (_Float16)cc[3]};
      *(half4v*)(&u.h[hswz(erow, 0 * 16 + kgrp * 4)]) = h4;
    }
    {
      floatx4 cc = {b1q1.x, b1q1.y, b1q1.z, b1q1.w};
      cc = __builtin_amdgcn_mfma_f32_16x16x32_f16(wA1, bg, cc, 0, 0, 0);
      half4v h4 = {(_Float16)cc[0], (_Float16)cc[1], (_Float16)cc[2], (_Float16)cc[3]};
      *(half4v*)(&u.h[hswz(erow, 1 * 16 + kgrp * 4)]) = h4;
    }
    {
      floatx4 cc = {b1q2.x, b1q2.y, b1q2.z, b1q2.w};
      cc = __builtin_amdgcn_mfma_f32_16x16x32_f16(wA2, bg, cc, 0, 0, 0);
      half4v h4 = {(_Float16)cc[0], (_Float16)cc[1], (_Float16)cc[2], (_Float16)cc[3]};
      *(half4v*)(&u.h[hswz(erow, 2 * 16 + kgrp * 4)]) = h4;
    }
    {
      floatx4 cc = {b1q3.x, b1q3.y, b1q3.z, b1q3.w};
      cc = __builtin_amdgcn_mfma_f32_16x16x32_f16(wA3, bg, cc, 0, 0, 0);
      half4v h4 = {(_Float16)cc[0], (_Float16)cc[1], (_Float16)cc[2], (_Float16)cc[3]};
      *(half4v*)(&u.h[hswz(erow, 3 * 16 + kgrp * 4)]) = h4;
    }
    __builtin_amdgcn_s_setprio(0);
  }
  // phases 0-2 touch only this wave's h rows: wave-local, no block barrier

  // ---- phase 1: h = relu(A[r] + B[c] + eaw) packed f16, RMW on own row ----
#pragma unroll
  for (int q = 0; q < 8; ++q) {
    int idx = hswz(tid, q * 8);
    half8 w = *(const half8*)(&u.h[idx]);
    half8 s = Ar[q] + Bc[q] + w;
    short8 sb = __builtin_bit_cast(short8, s);
    short8 m = sb >> 15;
    sb = sb & ~m;  // relu: zero negatives (and -0)
    *(short8*)(&u.h[idx]) = sb;
  }

  // ---- phase 2: layer-2 MFMA, 4 groups of 16 edges per wave ----
  const _Float16* wpp = w2pk + (size_t)lane * 32;
  half8 w2f00 = *(const half8*)(wpp);
  half8 w2f01 = *(const half8*)(wpp + 8);
  half8 w2f10 = *(const half8*)(wpp + 16);
  half8 w2f11 = *(const half8*)(wpp + 24);
  floatx4 acc[4][2];
  __builtin_amdgcn_s_setprio(1);  // T5: favor MFMA-phase waves
#pragma unroll
  for (int g = 0; g < 4; ++g) {
    int erow = wid * 64 + g * 16 + lcol;
    half8 a0 = *(const half8*)(&u.h[hswz(erow, kgrp * 8)]);
    half8 a1 = *(const half8*)(&u.h[hswz(erow, 32 + kgrp * 8)]);
    floatx4 c0 = {b2c0, b2c0, b2c0, b2c0};
    floatx4 c1 = {b2c1, b2c1, b2c1, b2c1};
    c0 = __builtin_amdgcn_mfma_f32_16x16x32_f16(a0, w2f00, c0, 0, 0, 0);
    c0 = __builtin_amdgcn_mfma_f32_16x16x32_f16(a1, w2f10, c0, 0, 0, 0);
    c1 = __builtin_amdgcn_mfma_f32_16x16x32_f16(a0, w2f01, c1, 0, 0, 0);
    c1 = __builtin_amdgcn_mfma_f32_16x16x32_f16(a1, w2f11, c1, 0, 0, 0);
    acc[g][0] = c0;
    acc[g][1] = c1;
  }
  __builtin_amdgcn_s_setprio(0);

  // EARLY-ISSUE: outb rows for the epilogue, overlapping the barrier wait.
  half8 Or[4], Oc[4];
  {
    const half8* orp = (const half8*)(outb + (size_t)r * DF);
    const half8* ocp = (const half8*)(outb + (size_t)c * DF);
#pragma unroll
    for (int q = 0; q < 4; ++q) { Or[q] = orp[q]; Oc[q] = ocp[q]; }
  }

  // RACE FIX: all waves must finish phase-2 h reads before any sh writes
  // (the two union views have different row strides -> cross-wave overlap).
  __syncthreads();

  // ---- phase 3a: dump o (C-frags) to LDS, stride-33 f32 rows ----
#pragma unroll
  for (int g = 0; g < 4; ++g) {
#pragma unroll
    for (int rr = 0; rr < 4; ++rr) {
      int e = wid * 64 + g * 16 + kgrp * 4 + rr;
      u.sh[e * 33 + lcol]      = acc[g][0][rr];
      u.sh[e * 33 + 16 + lcol] = acc[g][1][rr];
    }
  }

  // ---- phase 3b: owner-centric norm + mask + shift (all wave-local) ----
  {
    float o2[32];
    float nsq = 0.f;
#pragma unroll
    for (int j = 0; j < 32; ++j) {
      float v = u.sh[tid * 33 + j];
      o2[j] = v;
      nsq = fmaf(v, v, nsq);
    }
    float ms = (nsq > 0.f) ? rsqrtf(nsq) : 0.f;
    if (s_r == 0.f && s_c == 0.f) ms = 0.f;
#pragma unroll
    for (int q = 0; q < 4; ++q) {
#pragma unroll
      for (int jj = 0; jj < 8; ++jj)
        u.sh[tid * 33 + q * 8 + jj] =
            ((float)Oc[q][jj] - (float)Or[q][jj]) * o2[q * 8 + jj] * ms;
    }
  }
  __syncthreads();  // cross-wave: sh rows + scol + cnt now visible

  // ---- phase 4: segmented reduce over sorted-col runs ----
  int c_self = scol[tid];
  bool head = (tid == 0 || scol[tid - 1] != c_self);
  unsigned long long m = __ballot(head);
  if (lane == 0) wbase[wid] = atomicAdd(&cnt, (int)__popcll(m));
  __syncthreads();
  if (head) {
    int idx = wbase[wid] + (int)__popcll(m & ((1ull << lane) - 1ull));
    int t1 = tid + 1;
    while (t1 < 256 && scol[t1] == c_self) ++t1;
    l0[idx] = (unsigned short)tid;
    l1[idx] = (unsigned short)t1;
  }
  __syncthreads();
  int nr = cnt;
  for (int task = tid; task < nr * 32; task += 256) {
    int rid = task >> 5, j = task & 31;
    int t0 = l0[rid], t1 = l1[rid];
    float s = 0.f;
    for (int t = t0; t < t1; ++t) s += u.sh[t * 33 + j];
    unsafeAtomicAdd(&scattered[(size_t)scol[t0] * DF + j], s);
  }
}

// --- final node update (k=1): out += scattered @ Fk (in place, trimmed) ---
__global__ __launch_bounds__(256) void node_final_kernel(
    float* __restrict__ out, const float* __restrict__ scattered,
    const float* __restrict__ Fk) {
  int n = blockIdx.x * 256 + threadIdx.x;
  if (n >= NN) return;
  float s[DF];
  const float4* sp = reinterpret_cast<const float4*>(scattered + (size_t)n * DF);
#pragma unroll
  for (int q = 0; q < 8; ++q) {
    float4 v = sp[q];
    s[4*q+0]=v.x; s[4*q+1]=v.y; s[4*q+2]=v.z; s[4*q+3]=v.w;
  }
  float4* op = reinterpret_cast<float4*>(out + (size_t)n * DF);
#pragma unroll
  for (int q = 0; q < 8; ++q) {
    float4 acc = op[q];
#pragma unroll
    for (int i = 0; i < DF; ++i) {
      float si = s[i];
      acc.x = fmaf(si, Fk[i*DF + 4*q+0], acc.x);
      acc.y = fmaf(si, Fk[i*DF + 4*q+1], acc.y);
      acc.z = fmaf(si, Fk[i*DF + 4*q+2], acc.z);
      acc.w = fmaf(si, Fk[i*DF + 4*q+3], acc.w);
    }
    op[q] = acc;
  }
}

extern "C" void kernel_launch(void* const* d_in, const int* in_sizes, int n_in,
                              void* d_out, int out_size, void* d_ws, size_t ws_size,
                              hipStream_t stream) {
  const float* x_s = (const float*)d_in[0];
  const float* x_t = (const float*)d_in[1];
  const int*   ei  = (const int*)d_in[2];
  const float* ea  = (const float*)d_in[3];
  const float* W1  = (const float*)d_in[4];
  const float* b1  = (const float*)d_in[5];
  const float* W2  = (const float*)d_in[6];
  const float* b2  = (const float*)d_in[7];
  const float* F   = (const float*)d_in[8];

  float* out = (float*)d_out;
  char* ws = (char*)d_ws;
  float*     scattered = (float*)(ws);                  // 12.8 MB
  _Float16*  ABh       = (_Float16*)(ws + 12800000);    // 25.6 MB
  _Float16*  outb      = (_Float16*)(ws + 38400000);    // 6.4 MB
  float*     sums      = (float*)(ws + 44800000);       // 0.4 MB
  char*      recs      = (char*)(ws + 45200000);        // 51.2 MB (32B/edge)
  int*       deg       = (int*)(ws + 96400000);         // 0.4 MB
  int*       cur       = (int*)(ws + 96800000);         // 0.4 MB
  int*       bsums     = (int*)(ws + 97200000);         // 4 KB
  _Float16*  WpreT     = (_Float16*)(ws + 97210000);    // 16 KB
  _Float16*  w2pk      = (_Float16*)(ws + 97230000);    // 4 KB
  _Float16*  w1epk     = (_Float16*)(ws + 97240000);    // 4 KB

  dim3 blk(256);
  dim3 grid_e(NE / 256);          // 6250, exact
  dim3 grid_n((NN + 255) / 256);  // 391
  dim3 grid_p((NN + 63) / 64);    // 1563
  int nscan = (NN + 1023) / 1024; // 98

  hipMemsetAsync(deg, 0, NN * sizeof(int), stream);
  setup_kernel<<<grid_e, blk, 0, stream>>>(ei, W1, W2, WpreT, w2pk, w1epk,
                                           (float4*)scattered, deg);
  scan1_kernel<<<nscan, blk, 0, stream>>>(deg, cur, bsums);
  scan3_kernel<<<grid_n, blk, 0, stream>>>(cur, bsums);
  fill_kernel<<<grid_e, blk, 0, stream>>>(ei, ea, cur, recs);

  initpre_kernel<<<grid_p, blk, 0, stream>>>(x_t, F, x_s, WpreT,
                                             out, outb, sums, ABh);
  edge_kernel<<<grid_e, blk, 0, stream>>>(ABh, outb, sums, recs, b1, b2,
                                          w2pk, w1epk, scattered);
  nodepre_kernel<<<grid_p, blk, 0, stream>>>(out, scattered,
                                             F + (size_t)1 * DF * DF,
                                             x_s, WpreT, outb, sums, ABh);
  edge_kernel<<<grid_e, blk, 0, stream>>>(ABh, outb, sums, recs, b1, b2,
                                          w2pk, w1epk, scattered);
  node_final_kernel<<<grid_n, blk, 0, stream>>>(out, scattered,
                                                F + (size_t)2 * DF * DF);
}

// Round 20
// 434.396 us; speedup vs baseline: 1.0531x; 1.0531x over previous
//
#include <hip/hip_runtime.h>

#define NN 100000
#define NE 1600000
#define SF 16
#define DF 32
#define EFT 8
#define HF 64

typedef __attribute__((ext_vector_type(8))) _Float16 half8;
typedef __attribute__((ext_vector_type(4))) _Float16 half4v;
typedef __attribute__((ext_vector_type(8))) short short8;
typedef __attribute__((ext_vector_type(4))) float floatx4;

// swizzled half-index into the [256][64] h tile (128B rows, 16B-granule XOR)
__device__ inline int hswz(int row, int halfoff) {
  int gran = halfoff >> 3, sub = halfoff & 7;
  return row * 64 + ((gran ^ (row & 7)) << 3) + sub;
}

// ---------------- CSR scan ----------------
__global__ __launch_bounds__(256) void scan1_kernel(const int* __restrict__ deg,
                                                    int* __restrict__ cur,
                                                    int* __restrict__ bsums) {
  __shared__ int ts[256];
  int tid = threadIdx.x;
  int base = blockIdx.x * 1024 + tid * 4;
  int v[4];
#pragma unroll
  for (int q = 0; q < 4; ++q) v[q] = (base + q < NN) ? deg[base + q] : 0;
  int s = v[0] + v[1] + v[2] + v[3];
  ts[tid] = s;
  __syncthreads();
  for (int off = 1; off < 256; off <<= 1) {
    int t = (tid >= off) ? ts[tid - off] : 0;
    __syncthreads();
    ts[tid] += t;
    __syncthreads();
  }
  int excl = ts[tid] - s;
  if (tid == 255) bsums[blockIdx.x] = ts[255];
  int run = excl;
#pragma unroll
  for (int q = 0; q < 4; ++q) {
    if (base + q < NN) cur[base + q] = run;
    run += v[q];
  }
}

__global__ __launch_bounds__(256) void scan3_kernel(int* __restrict__ cur,
                                                    const int* __restrict__ bsums) {
  int i = blockIdx.x * 256 + threadIdx.x;
  int g = blockIdx.x >> 2;
  int pref = 0;
  for (int q = 0; q < g; ++q) pref += bsums[q];
  if (i < NN) cur[i] += pref;
}

// ---- setup (grid 6250): zero scattered; pack tables; hist (deg pre-zeroed) ----
__global__ __launch_bounds__(256) void setup_kernel(
    const int* __restrict__ ei,
    const float* __restrict__ W1, const float* __restrict__ W2,
    _Float16* __restrict__ WpreT, _Float16* __restrict__ w2pk,
    _Float16* __restrict__ w1epk,
    float4* __restrict__ scattered4, int* __restrict__ deg) {
  int gid = blockIdx.x * 256 + threadIdx.x;
  if (gid < 800000) {
    float4 z = {0.f, 0.f, 0.f, 0.f};
    scattered4[gid] = z;
  }
  if (gid < 128 * 64) {
    int col = gid >> 6, k = gid & 63;
    int j = col & 63;
    bool bh = col >= 64;
    float v = 0.f;
    if (k < 16) v = W1[((bh ? 16 : 0) + k) * HF + j];
    else if (k < 48) v = W1[((bh ? 64 : 32) + (k - 16)) * HF + j];
    WpreT[gid] = (_Float16)v;
  }
  if (gid < 2048) {
    // W2 B-frags: lane holds col = nt*16+lcol, k = kt*32 + kgrp*8 + q
    int lane = gid >> 5, idx = gid & 31;
    int kt = idx >> 4, nt = (idx >> 3) & 1, q = idx & 7;
    int kgrp = (lane >> 4) & 3, lcol = lane & 15;
    w2pk[gid] = (_Float16)W2[(kt * 32 + kgrp * 8 + q) * DF + nt * 16 + lcol];
  } else if (gid < 4096) {
    // W1e^T A-frags: lane<16 holds row j=lane (within jblk), k=t (k>=8 -> 0)
    int id = gid - 2048;  // lane*32 + jblk*8 + t
    int lane = id >> 5, idx = id & 31;
    int jblk = idx >> 3, t = idx & 7;
    float v = (lane < 16) ? W1[(96 + t) * HF + jblk * 16 + lane] : 0.f;
    w1epk[id] = (_Float16)v;
  }
  // hist (deg zeroed by hipMemsetAsync before this kernel)
  atomicAdd(&deg[ei[NE + gid]], 1);
}

// ---- fill: packed 32B-aligned sorted records {int r, int c, half ea[8], pad} ----
__global__ __launch_bounds__(256) void fill_kernel(
    const int* __restrict__ ei, const float* __restrict__ ea,
    int* __restrict__ cur, char* __restrict__ recs) {
  int e = blockIdx.x * 256 + threadIdx.x;
  int r = ei[e];
  int c = ei[NE + e];
  int pos = atomicAdd(&cur[c], 1);
  const float4* p = (const float4*)(ea + (size_t)e * EFT);
  float4 v0 = p[0], v1 = p[1];
  union { _Float16 h[2]; int i; } p01, p23, p45, p67;
  p01.h[0] = (_Float16)v0.x; p01.h[1] = (_Float16)v0.y;
  p23.h[0] = (_Float16)v0.z; p23.h[1] = (_Float16)v0.w;
  p45.h[0] = (_Float16)v1.x; p45.h[1] = (_Float16)v1.y;
  p67.h[0] = (_Float16)v1.z; p67.h[1] = (_Float16)v1.w;
  int4* rp = (int4*)(recs + (size_t)pos * 32);
  int4 a = {r, c, p01.i, p23.i};
  int4 b = {p45.i, p67.i, 0, 0};
  rp[0] = a;
  rp[1] = b;
}

// ---- shared pre-body: MFMA ABh for 64 nodes of this block, outb rows in obs ----
__device__ inline void pre_body(int tid, int bbase64,
                                const float* __restrict__ x_s,
                                const _Float16 (*wlds)[72],
                                const _Float16 (*obs)[32],
                                _Float16* __restrict__ ABh) {
  int lcol = tid & 15, kgrp = (tid >> 4) & 3, wid = tid >> 6;
  int nodebase = bbase64 + wid * 16;
  int nodeA = nodebase + lcol;
  int ln = wid * 16 + lcol;

  half8 a0 = {}, a1 = {};
  if (nodeA < NN) {
    if (kgrp < 2) {
      const float4* p = (const float4*)(x_s + (size_t)nodeA * SF);
      float4 v0 = p[kgrp * 2], v1 = p[kgrp * 2 + 1];
      a0[0]=(_Float16)v0.x; a0[1]=(_Float16)v0.y;
      a0[2]=(_Float16)v0.z; a0[3]=(_Float16)v0.w;
      a0[4]=(_Float16)v1.x; a0[5]=(_Float16)v1.y;
      a0[6]=(_Float16)v1.z; a0[7]=(_Float16)v1.w;
      a1 = *(const half8*)(&obs[ln][16 + kgrp * 8]);
    } else if (kgrp == 2) {
      a0 = *(const half8*)(&obs[ln][0]);
    } else {
      a0 = *(const half8*)(&obs[ln][8]);
    }
  }

  floatx4 acc[8];
#pragma unroll
  for (int nt = 0; nt < 8; ++nt) {
    half8 b0 = *(const half8*)(&wlds[nt * 16 + lcol][kgrp * 8]);
    half8 b1v = *(const half8*)(&wlds[nt * 16 + lcol][32 + kgrp * 8]);
    floatx4 c = {0.f, 0.f, 0.f, 0.f};
    c = __builtin_amdgcn_mfma_f32_16x16x32_f16(a0, b0, c, 0, 0, 0);
    c = __builtin_amdgcn_mfma_f32_16x16x32_f16(a1, b1v, c, 0, 0, 0);
    acc[nt] = c;
  }

#pragma unroll
  for (int rr = 0; rr < 4; ++rr) {
    int node = nodebase + kgrp * 4 + rr;
    if (node < NN) {
      _Float16* dst = ABh + (size_t)node * 128;
#pragma unroll
      for (int nt = 0; nt < 8; ++nt)
        dst[nt * 16 + lcol] = (_Float16)acc[nt][rr];
    }
  }
}

// ---- initpre (grid 1563): out = x_t @ F0; outb/sums; then pre MFMA ----
__global__ __launch_bounds__(256) void initpre_kernel(
    const float* __restrict__ x_t, const float* __restrict__ F0,
    const float* __restrict__ x_s, const _Float16* __restrict__ WpreT,
    float* __restrict__ out, _Float16* __restrict__ outb,
    float* __restrict__ sums, _Float16* __restrict__ ABh) {
  __shared__ _Float16 wlds[128][72];
  __shared__ _Float16 obs[64][32];
  int tid = threadIdx.x;
  for (int t = tid; t < 1024; t += 256) {
    int colr = t >> 3, kc = t & 7;
    *(half8*)(&wlds[colr][kc * 8]) = *(const half8*)(WpreT + colr * 64 + kc * 8);
  }

  int nl = tid >> 2, q = tid & 3;
  int node = blockIdx.x * 64 + nl;
  if (node < NN) {
    float o[8];
#pragma unroll
    for (int jj = 0; jj < 8; ++jj) o[jj] = 0.f;
    const float4* xt4 = (const float4*)(x_t + (size_t)node * DF);
#pragma unroll
    for (int it = 0; it < 8; ++it) {
      float4 xv = xt4[it];
#pragma unroll
      for (int k = 0; k < 4; ++k) {
        float xk = (k == 0) ? xv.x : (k == 1) ? xv.y : (k == 2) ? xv.z : xv.w;
        const float* frow = F0 + (it * 4 + k) * DF + q * 8;
        float4 f0 = *(const float4*)(frow);
        float4 f1 = *(const float4*)(frow + 4);
        o[0] = fmaf(xk, f0.x, o[0]); o[1] = fmaf(xk, f0.y, o[1]);
        o[2] = fmaf(xk, f0.z, o[2]); o[3] = fmaf(xk, f0.w, o[3]);
        o[4] = fmaf(xk, f1.x, o[4]); o[5] = fmaf(xk, f1.y, o[5]);
        o[6] = fmaf(xk, f1.z, o[6]); o[7] = fmaf(xk, f1.w, o[7]);
      }
    }
    float4* op = (float4*)(out + (size_t)node * DF + q * 8);
    float4 w0 = {o[0], o[1], o[2], o[3]};
    float4 w1 = {o[4], o[5], o[6], o[7]};
    op[0] = w0; op[1] = w1;
    half8 pk;
#pragma unroll
    for (int jj = 0; jj < 8; ++jj) pk[jj] = (_Float16)o[jj];
    *(half8*)(outb + (size_t)node * DF + q * 8) = pk;
    *(half8*)(&obs[nl][q * 8]) = pk;
    float s = o[0]+o[1]+o[2]+o[3]+o[4]+o[5]+o[6]+o[7];
    s += __shfl_xor(s, 1, 64);
    s += __shfl_xor(s, 2, 64);
    if (q == 0) sums[node] = s;
  }
  __syncthreads();
  pre_body(tid, blockIdx.x * 64, x_s, wlds, obs, ABh);
}

// ---- nodepre (grid 1563): out += scattered @ Fk; zero scattered; pre MFMA ----
__global__ __launch_bounds__(256) void nodepre_kernel(
    float* __restrict__ out, float* __restrict__ scattered,
    const float* __restrict__ Fk,
    const float* __restrict__ x_s, const _Float16* __restrict__ WpreT,
    _Float16* __restrict__ outb, float* __restrict__ sums,
    _Float16* __restrict__ ABh) {
  __shared__ _Float16 wlds[128][72];
  __shared__ _Float16 obs[64][32];
  int tid = threadIdx.x;
  for (int t = tid; t < 1024; t += 256) {
    int colr = t >> 3, kc = t & 7;
    *(half8*)(&wlds[colr][kc * 8]) = *(const half8*)(WpreT + colr * 64 + kc * 8);
  }

  int nl = tid >> 2, q = tid & 3;
  int node = blockIdx.x * 64 + nl;
  if (node < NN) {
    float o[8];
    {
      const float4* op4 = (const float4*)(out + (size_t)node * DF + q * 8);
      float4 b0 = op4[0], b1 = op4[1];
      o[0]=b0.x; o[1]=b0.y; o[2]=b0.z; o[3]=b0.w;
      o[4]=b1.x; o[5]=b1.y; o[6]=b1.z; o[7]=b1.w;
    }
    const float4* sc4 = (const float4*)(scattered + (size_t)node * DF);
#pragma unroll
    for (int it = 0; it < 8; ++it) {
      float4 sv = sc4[it];
#pragma unroll
      for (int k = 0; k < 4; ++k) {
        float sk = (k == 0) ? sv.x : (k == 1) ? sv.y : (k == 2) ? sv.z : sv.w;
        const float* frow = Fk + (it * 4 + k) * DF + q * 8;
        float4 f0 = *(const float4*)(frow);
        float4 f1 = *(const float4*)(frow + 4);
        o[0] = fmaf(sk, f0.x, o[0]); o[1] = fmaf(sk, f0.y, o[1]);
        o[2] = fmaf(sk, f0.z, o[2]); o[3] = fmaf(sk, f0.w, o[3]);
        o[4] = fmaf(sk, f1.x, o[4]); o[5] = fmaf(sk, f1.y, o[5]);
        o[6] = fmaf(sk, f1.z, o[6]); o[7] = fmaf(sk, f1.w, o[7]);
      }
    }
    float4* op = (float4*)(out + (size_t)node * DF + q * 8);
    float4 w0 = {o[0], o[1], o[2], o[3]};
    float4 w1 = {o[4], o[5], o[6], o[7]};
    op[0] = w0; op[1] = w1;
    half8 pk;
#pragma unroll
    for (int jj = 0; jj < 8; ++jj) pk[jj] = (_Float16)o[jj];
    *(half8*)(outb + (size_t)node * DF + q * 8) = pk;
    *(half8*)(&obs[nl][q * 8]) = pk;
    float s = o[0]+o[1]+o[2]+o[3]+o[4]+o[5]+o[6]+o[7];
    s += __shfl_xor(s, 1, 64);
    s += __shfl_xor(s, 2, 64);
    if (q == 0) sums[node] = s;
    // zero own quarter of scattered (loads above already consumed: the FMA
    // chain forces vmcnt wait before these stores issue)
    float4 z = {0.f, 0.f, 0.f, 0.f};
    float4* zp = (float4*)(scattered + (size_t)node * DF + q * 8);
    zp[0] = z; zp[1] = z;
  }
  __syncthreads();
  pre_body(tid, blockIdx.x * 64, x_s, wlds, obs, ABh);
}

// ---------------- edge MLP (f16 MFMA) + owner-centric epilogue ----------------
__global__ __launch_bounds__(256, 4) void edge_kernel(
    const _Float16* __restrict__ ABh, const _Float16* __restrict__ outb,
    const float* __restrict__ sums, const char* __restrict__ recs,
    const float* __restrict__ b1, const float* __restrict__ b2,
    const _Float16* __restrict__ w2pk, const _Float16* __restrict__ w1epk,
    float* __restrict__ scattered) {
  // h: [256][64] halves, 128B rows, XOR-swizzled granules (32768 B)
  // sh: [256] rows of 33 f32 (33792 B) -> union 33792 B
  __shared__ union { _Float16 h[256 * 64]; float sh[256 * 33]; } u;
  __shared__ int scol[256];
  __shared__ unsigned short l0[256], l1[256];
  __shared__ int wbase[4];
  __shared__ int cnt;

  int tid = threadIdx.x;
  int bbase = blockIdx.x * 256;
  int i = bbase + tid;  // NE % 256 == 0: always valid
  if (tid == 0) cnt = 0;
  int lcol = tid & 15, kgrp = (tid >> 4) & 3, wid = tid >> 6;
  int lane = tid & 63;

  // load packed 32B record {r, c, ea[8] f16, pad}
  const int4* rp = (const int4*)(recs + (size_t)i * 32);
  int4 ra = rp[0];
  int4 rb = rp[1];
  int r = ra.x;
  int c = ra.y;
  int4 eai = {ra.z, ra.w, rb.x, rb.y};
  scol[tid] = c;
  float s_r = sums[r], s_c = sums[c];

  // EARLY-ISSUE: stage A[r] and B[c] halves (128B each) into registers so
  // the HBM/L3 latency hides under phase-0's shuffles + MFMAs.
  half8 Ar[8], Bc[8];
  {
    const half8* arp = (const half8*)(ABh + (size_t)r * 128);
    const half8* bcp = (const half8*)(ABh + (size_t)c * 128 + 64);
#pragma unroll
    for (int q = 0; q < 8; ++q) { Ar[q] = arp[q]; Bc[q] = bcp[q]; }
  }

  float b2c0 = b2[lcol], b2c1 = b2[16 + lcol];

  // ---- phase 0: eaw^T = W1e^T @ ea via swapped MFMA -> swizzled half4 writes ----
  const _Float16* wep = w1epk + (size_t)lane * 32;
  half8 wA0 = *(const half8*)(wep);
  half8 wA1 = *(const half8*)(wep + 8);
  half8 wA2 = *(const half8*)(wep + 16);
  half8 wA3 = *(const half8*)(wep + 24);
  const float4* b1f4 = (const float4*)b1;
  float4 b1q0 = b1f4[0 + kgrp];
  float4 b1q1 = b1f4[4 + kgrp];
  float4 b1q2 = b1f4[8 + kgrp];
  float4 b1q3 = b1f4[12 + kgrp];
  bool lo16 = lane < 16;
#pragma unroll
  for (int g = 0; g < 4; ++g) {
    int src = g * 16 + lcol;
    int4 t;
    t.x = __shfl(eai.x, src, 64);
    t.y = __shfl(eai.y, src, 64);
    t.z = __shfl(eai.z, src, 64);
    t.w = __shfl(eai.w, src, 64);
    half8 zz = {};
    half8 bg = lo16 ? __builtin_bit_cast(half8, t) : zz;
    int erow = wid * 64 + g * 16 + lcol;
    {
      floatx4 cc = {b1q0.x, b1q0.y, b1q0.z, b1q0.w};
      cc = __builtin_amdgcn_mfma_f32_16x16x32_f16(wA0, bg, cc, 0, 0, 0);
      half4v h4 = {(_Float16)cc[0], (_Float16)cc[1], (_Float16)cc[2], (_Float16)cc[3]};
      *(half4v*)(&u.h[hswz(erow, 0 * 16 + kgrp * 4)]) = h4;
    }
    {
      floatx4 cc = {b1q1.x, b1q1.y, b1q1.z, b1q1.w};
      cc = __builtin_amdgcn_mfma_f32_16x16x32_f16(wA1, bg, cc, 0, 0, 0);
      half4v h4 = {(_Float16)cc[0], (_Float16)cc[1], (_Float16)cc[2], (_Float16)cc[3]};
      *(half4v*)(&u.h[hswz(erow, 1 * 16 + kgrp * 4)]) = h4;
    }
    {
      floatx4 cc = {b1q2.x, b1q2.y, b1q2.z, b1q2.w};
      cc = __builtin_amdgcn_mfma_f32_16x16x32_f16(wA2, bg, cc, 0, 0, 0);
      half4v h4 = {(_Float16)cc[0], (_Float16)cc[1], (_Float16)cc[2], (_Float16)cc[3]};
      *(half4v*)(&u.h[hswz(erow, 2 * 16 + kgrp * 4)]) = h4;
    }
    {
      floatx4 cc = {b1q3.x, b1q3.y, b1q3.z, b1q3.w};
      cc = __builtin_amdgcn_mfma_f32_16x16x32_f16(wA3, bg, cc, 0, 0, 0);
      half4v h4 = {(_Float16)cc[0], (_Float16)cc[1], (_Float16)cc[2], (_Float16)cc[3]};
      *(half4v*)(&u.h[hswz(erow, 3 * 16 + kgrp * 4)]) = h4;
    }
  }
  // phases 0-2 touch only this wave's h rows: wave-local, no block barrier

  // ---- phase 1: h = relu(A[r] + B[c] + eaw) packed f16, RMW on own row ----
#pragma unroll
  for (int q = 0; q < 8; ++q) {
    int idx = hswz(tid, q * 8);
    half8 w = *(const half8*)(&u.h[idx]);
    half8 s = Ar[q] + Bc[q] + w;
    short8 sb = __builtin_bit_cast(short8, s);
    short8 m = sb >> 15;
    sb = sb & ~m;  // relu: zero negatives (and -0)
    *(short8*)(&u.h[idx]) = sb;
  }

  // ---- phase 2: layer-2 MFMA, 4 groups of 16 edges per wave ----
  const _Float16* wpp = w2pk + (size_t)lane * 32;
  half8 w2f00 = *(const half8*)(wpp);
  half8 w2f01 = *(const half8*)(wpp + 8);
  half8 w2f10 = *(const half8*)(wpp + 16);
  half8 w2f11 = *(const half8*)(wpp + 24);
  floatx4 acc[4][2];
#pragma unroll
  for (int g = 0; g < 4; ++g) {
    int erow = wid * 64 + g * 16 + lcol;
    half8 a0 = *(const half8*)(&u.h[hswz(erow, kgrp * 8)]);
    half8 a1 = *(const half8*)(&u.h[hswz(erow, 32 + kgrp * 8)]);
    floatx4 c0 = {b2c0, b2c0, b2c0, b2c0};
    floatx4 c1 = {b2c1, b2c1, b2c1, b2c1};
    c0 = __builtin_amdgcn_mfma_f32_16x16x32_f16(a0, w2f00, c0, 0, 0, 0);
    c0 = __builtin_amdgcn_mfma_f32_16x16x32_f16(a1, w2f10, c0, 0, 0, 0);
    c1 = __builtin_amdgcn_mfma_f32_16x16x32_f16(a0, w2f01, c1, 0, 0, 0);
    c1 = __builtin_amdgcn_mfma_f32_16x16x32_f16(a1, w2f11, c1, 0, 0, 0);
    acc[g][0] = c0;
    acc[g][1] = c1;
  }

  // EARLY-ISSUE: outb rows for the epilogue, overlapping the barrier wait.
  half8 Or[4], Oc[4];
  {
    const half8* orp = (const half8*)(outb + (size_t)r * DF);
    const half8* ocp = (const half8*)(outb + (size_t)c * DF);
#pragma unroll
    for (int q = 0; q < 4; ++q) { Or[q] = orp[q]; Oc[q] = ocp[q]; }
  }

  // RACE FIX: all waves must finish phase-2 h reads before any sh writes
  // (the two union views have different row strides -> cross-wave overlap).
  __syncthreads();

  // ---- phase 3a: dump o (C-frags) to LDS, stride-33 f32 rows ----
#pragma unroll
  for (int g = 0; g < 4; ++g) {
#pragma unroll
    for (int rr = 0; rr < 4; ++rr) {
      int e = wid * 64 + g * 16 + kgrp * 4 + rr;
      u.sh[e * 33 + lcol]      = acc[g][0][rr];
      u.sh[e * 33 + 16 + lcol] = acc[g][1][rr];
    }
  }

  // ---- phase 3b: owner-centric norm + mask + shift (all wave-local) ----
  {
    float o2[32];
    float nsq = 0.f;
#pragma unroll
    for (int j = 0; j < 32; ++j) {
      float v = u.sh[tid * 33 + j];
      o2[j] = v;
      nsq = fmaf(v, v, nsq);
    }
    float ms = (nsq > 0.f) ? rsqrtf(nsq) : 0.f;
    if (s_r == 0.f && s_c == 0.f) ms = 0.f;
#pragma unroll
    for (int q = 0; q < 4; ++q) {
#pragma unroll
      for (int jj = 0; jj < 8; ++jj)
        u.sh[tid * 33 + q * 8 + jj] =
            ((float)Oc[q][jj] - (float)Or[q][jj]) * o2[q * 8 + jj] * ms;
    }
  }
  __syncthreads();  // cross-wave: sh rows + scol + cnt now visible

  // ---- phase 4: segmented reduce over sorted-col runs ----
  int c_self = scol[tid];
  bool head = (tid == 0 || scol[tid - 1] != c_self);
  unsigned long long m = __ballot(head);
  if (lane == 0) wbase[wid] = atomicAdd(&cnt, (int)__popcll(m));
  __syncthreads();
  if (head) {
    int idx = wbase[wid] + (int)__popcll(m & ((1ull << lane) - 1ull));
    int t1 = tid + 1;
    while (t1 < 256 && scol[t1] == c_self) ++t1;
    l0[idx] = (unsigned short)tid;
    l1[idx] = (unsigned short)t1;
  }
  __syncthreads();
  int nr = cnt;
  for (int task = tid; task < nr * 32; task += 256) {
    int rid = task >> 5, j = task & 31;
    int t0 = l0[rid], t1 = l1[rid];
    float s = 0.f;
    for (int t = t0; t < t1; ++t) s += u.sh[t * 33 + j];
    unsafeAtomicAdd(&scattered[(size_t)scol[t0] * DF + j], s);
  }
}

// --- final node update (k=1): out += scattered @ Fk (in place, trimmed) ---
__global__ __launch_bounds__(256) void node_final_kernel(
    float* __restrict__ out, const float* __restrict__ scattered,
    const float* __restrict__ Fk) {
  int n = blockIdx.x * 256 + threadIdx.x;
  if (n >= NN) return;
  float s[DF];
  const float4* sp = reinterpret_cast<const float4*>(scattered + (size_t)n * DF);
#pragma unroll
  for (int q = 0; q < 8; ++q) {
    float4 v = sp[q];
    s[4*q+0]=v.x; s[4*q+1]=v.y; s[4*q+2]=v.z; s[4*q+3]=v.w;
  }
  float4* op = reinterpret_cast<float4*>(out + (size_t)n * DF);
#pragma unroll
  for (int q = 0; q < 8; ++q) {
    float4 acc = op[q];
#pragma unroll
    for (int i = 0; i < DF; ++i) {
      float si = s[i];
      acc.x = fmaf(si, Fk[i*DF + 4*q+0], acc.x);
      acc.y = fmaf(si, Fk[i*DF + 4*q+1], acc.y);
      acc.z = fmaf(si, Fk[i*DF + 4*q+2], acc.z);
      acc.w = fmaf(si, Fk[i*DF + 4*q+3], acc.w);
    }
    op[q] = acc;
  }
}

extern "C" void kernel_launch(void* const* d_in, const int* in_sizes, int n_in,
                              void* d_out, int out_size, void* d_ws, size_t ws_size,
                              hipStream_t stream) {
  const float* x_s = (const float*)d_in[0];
  const float* x_t = (const float*)d_in[1];
  const int*   ei  = (const int*)d_in[2];
  const float* ea  = (const float*)d_in[3];
  const float* W1  = (const float*)d_in[4];
  const float* b1  = (const float*)d_in[5];
  const float* W2  = (const float*)d_in[6];
  const float* b2  = (const float*)d_in[7];
  const float* F   = (const float*)d_in[8];

  float* out = (float*)d_out;
  char* ws = (char*)d_ws;
  float*     scattered = (float*)(ws);                  // 12.8 MB
  _Float16*  ABh       = (_Float16*)(ws + 12800000);    // 25.6 MB
  _Float16*  outb      = (_Float16*)(ws + 38400000);    // 6.4 MB
  float*     sums      = (float*)(ws + 44800000);       // 0.4 MB
  char*      recs      = (char*)(ws + 45200000);        // 51.2 MB (32B/edge)
  int*       deg       = (int*)(ws + 96400000);         // 0.4 MB
  int*       cur       = (int*)(ws + 96800000);         // 0.4 MB
  int*       bsums     = (int*)(ws + 97200000);         // 4 KB
  _Float16*  WpreT     = (_Float16*)(ws + 97210000);    // 16 KB
  _Float16*  w2pk      = (_Float16*)(ws + 97230000);    // 4 KB
  _Float16*  w1epk     = (_Float16*)(ws + 97240000);    // 4 KB

  dim3 blk(256);
  dim3 grid_e(NE / 256);          // 6250, exact
  dim3 grid_n((NN + 255) / 256);  // 391
  dim3 grid_p((NN + 63) / 64);    // 1563
  int nscan = (NN + 1023) / 1024; // 98

  hipMemsetAsync(deg, 0, NN * sizeof(int), stream);
  setup_kernel<<<grid_e, blk, 0, stream>>>(ei, W1, W2, WpreT, w2pk, w1epk,
                                           (float4*)scattered, deg);
  scan1_kernel<<<nscan, blk, 0, stream>>>(deg, cur, bsums);
  scan3_kernel<<<grid_n, blk, 0, stream>>>(cur, bsums);
  fill_kernel<<<grid_e, blk, 0, stream>>>(ei, ea, cur, recs);

  initpre_kernel<<<grid_p, blk, 0, stream>>>(x_t, F, x_s, WpreT,
                                             out, outb, sums, ABh);
  edge_kernel<<<grid_e, blk, 0, stream>>>(ABh, outb, sums, recs, b1, b2,
                                          w2pk, w1epk, scattered);
  nodepre_kernel<<<grid_p, blk, 0, stream>>>(out, scattered,
                                             F + (size_t)1 * DF * DF,
                                             x_s, WpreT, outb, sums, ABh);
  edge_kernel<<<grid_e, blk, 0, stream>>>(ABh, outb, sums, recs, b1, b2,
                                          w2pk, w1epk, scattered);
  node_final_kernel<<<grid_n, blk, 0, stream>>>(out, scattered,
                                                F + (size_t)2 * DF * DF);
}